// Round 4
// baseline (523.489 us; speedup 1.0000x reference)
//
#include <hip/hip_runtime.h>
#include <math.h>

#define D 256
#define SCAN_CHUNK 1024
#define GPITCH 264    // bf16 LDS pitch for MFMA A tiles (pad 8) — verified pattern r3-r9
#define PPITCH 264    // product tile pitch for linkpred (same verified MFMA-A pattern)
#define NPN 4         // nodes per 4-lane group in chunked agg
#define NPB 256       // nodes per block in chunked agg (64 groups * NPN)

typedef __attribute__((ext_vector_type(8))) short frag_ab;   // 8 bf16
typedef __attribute__((ext_vector_type(4))) float frag_cd;   // 4 fp32

__device__ inline unsigned short f2b(float f) {
    unsigned int u = __float_as_uint(f);
    u += 0x7fffu + ((u >> 16) & 1u);
    return (unsigned short)(u >> 16);
}
__device__ inline float b2f(unsigned short h) {
    return __uint_as_float(((unsigned int)h) << 16);
}
// elementwise product of two packed bf16 pairs -> packed bf16 pair (TRUNCATING, 7 VALU ops)
__device__ inline unsigned int bmul2t(unsigned int a, unsigned int b) {
    float a0 = __uint_as_float(a << 16);
    float a1 = __uint_as_float(a & 0xffff0000u);
    float b0 = __uint_as_float(b << 16);
    float b1 = __uint_as_float(b & 0xffff0000u);
    float p0 = a0 * b0, p1 = a1 * b1;
    // out = (hi16(p1) << 16) | hi16(p0)
    return __builtin_amdgcn_perm(__float_as_uint(p1), __float_as_uint(p0), 0x07060302);
}

// ---------- zero int buffer ----------
__global__ void k_zero_int(int* p, int n) {
    int i = blockIdx.x * 256 + threadIdx.x;
    if (i < n) p[i] = 0;
}

// ---------- int degree count ----------
__global__ void k_count_int(const int* __restrict__ row, int* deg, int E) {
    int e = blockIdx.x * 256 + threadIdx.x;
    if (e < E) atomicAdd(&deg[row[e]], 1);
}

// ---------- prefix scan (3 stages); excl written into rowptr ----------
__global__ __launch_bounds__(256) void k_scan_block(const int* __restrict__ deg, int* __restrict__ excl,
                                                    int* __restrict__ bsums, int n) {
    __shared__ int s[256];
    int blk = blockIdx.x, t = threadIdx.x;
    int base = blk * SCAN_CHUNK + t * 4;
    int v0 = (base + 0 < n) ? deg[base + 0] : 0;
    int v1 = (base + 1 < n) ? deg[base + 1] : 0;
    int v2 = (base + 2 < n) ? deg[base + 2] : 0;
    int v3 = (base + 3 < n) ? deg[base + 3] : 0;
    int tsum = v0 + v1 + v2 + v3;
    s[t] = tsum;
    __syncthreads();
    for (int off = 1; off < 256; off <<= 1) {
        int x = (t >= off) ? s[t - off] : 0;
        __syncthreads();
        s[t] += x;
        __syncthreads();
    }
    int run = s[t] - tsum;
    if (t == 255) bsums[blk] = s[255];
    if (base + 0 < n) excl[base + 0] = run;
    run += v0;
    if (base + 1 < n) excl[base + 1] = run;
    run += v1;
    if (base + 2 < n) excl[base + 2] = run;
    run += v2;
    if (base + 3 < n) excl[base + 3] = run;
}

__global__ __launch_bounds__(256) void k_scan_bsums(int* bsums, int nb) {
    __shared__ int s[256];
    int t = threadIdx.x;
    int v = (t < nb) ? bsums[t] : 0;
    s[t] = v;
    __syncthreads();
    for (int off = 1; off < 256; off <<= 1) {
        int x = (t >= off) ? s[t - off] : 0;
        __syncthreads();
        s[t] += x;
        __syncthreads();
    }
    if (t < nb) bsums[t] = s[t] - v;
}

// fused: rowptr[i] += bsums[i/SCAN_CHUNK]  AND  dinv[i] = rsqrt(deg[i]+1)
__global__ void k_scan_add_dinv(int* __restrict__ rowptr, const int* __restrict__ bsums,
                                const int* __restrict__ deg, float* __restrict__ dinv,
                                int n, int total) {
    int i = blockIdx.x * 256 + threadIdx.x;
    if (i < n) {
        rowptr[i] += bsums[i / SCAN_CHUNK];
        dinv[i] = rsqrtf((float)(deg[i] + 1));
    }
    if (i == 0) rowptr[n] = total;
}

// ---------- bucket edges into CSR records {col, norm-weight} ----------
__global__ void k_bucket(const int* __restrict__ row, const int* __restrict__ col,
                         const int* __restrict__ rowptr, int* __restrict__ fill,
                         int2* __restrict__ erec, const float* __restrict__ dinv, int E) {
    int e = blockIdx.x * 256 + threadIdx.x;
    if (e >= E) return;
    int r = row[e];
    int c = col[e];
    int pos = atomicAdd(&fill[r], 1);
    erec[rowptr[r] + pos] = make_int2(c, __float_as_int(dinv[r] * dinv[c]));
}

// ---------- pack three fp32 [k][n] weights into MFMA B-fragment order (bf16) ----------
__global__ void k_packB3(const float* __restrict__ Wa, const float* __restrict__ Wb,
                         const float* __restrict__ Wc,
                         unsigned short* __restrict__ Ba, unsigned short* __restrict__ Bb,
                         unsigned short* __restrict__ Bc) {
    int which = blockIdx.x >> 8;
    int i = (blockIdx.x & 255) * 256 + threadIdx.x;   // 65536 per weight
    const float* W = (which == 0) ? Wa : (which == 1) ? Wb : Wc;
    unsigned short* Bp = (which == 0) ? Ba : (which == 1) ? Bb : Bc;
    int ntile = i >> 12;
    int kt = (i >> 9) & 7;
    int lane = (i >> 3) & 63;
    int j = i & 7;
    int k = kt * 32 + (lane >> 4) * 8 + j;
    int n = ntile * 16 + (lane & 15);
    Bp[i] = f2b(W[k * D + n]);
}

// ---------- MFMA GEMM: H16[nrows,256] = X[nrows,256] @ W  (bf16 in/out, fp32 acc) ----------
__global__ __launch_bounds__(256) void k_gemm_mfma(const void* __restrict__ X, int xIsF32,
                                                   const unsigned short* __restrict__ Bpack,
                                                   unsigned short* __restrict__ H, int nrows) {
    __shared__ unsigned short As[32 * GPITCH];
    int t = threadIdx.x;
    int rowBase = blockIdx.x * 32;

    {
        int half = t >> 7;
        int cpair = t & 127;
        for (int qi = 0; qi < 32; qi += 2) {
            int q = qi + half;
            int r = rowBase + q;
            unsigned int val = 0;
            if (r < nrows) {
                if (xIsF32) {
                    const float* xr = (const float*)X + (size_t)r * D + cpair * 2;
                    val = (unsigned int)f2b(xr[0]) | ((unsigned int)f2b(xr[1]) << 16);
                } else {
                    val = ((const unsigned int*)((const unsigned short*)X + (size_t)r * D))[cpair];
                }
            }
            *(unsigned int*)&As[q * GPITCH + cpair * 2] = val;
        }
    }
    __syncthreads();

    int w = t >> 6, lane = t & 63;
    int mtile = w >> 1;
    int nhalf = w & 1;
    int quad = lane >> 4, lcol = lane & 15;

    frag_cd acc[8];
    #pragma unroll
    for (int n = 0; n < 8; ++n) acc[n] = (frag_cd){0.f, 0.f, 0.f, 0.f};

    const frag_ab* bp = (const frag_ab*)Bpack;
    for (int kt = 0; kt < 8; ++kt) {
        frag_ab a = *(const frag_ab*)&As[(mtile * 16 + lcol) * GPITCH + kt * 32 + quad * 8];
        #pragma unroll
        for (int n = 0; n < 8; ++n) {
            frag_ab b = bp[((nhalf * 8 + n) * 8 + kt) * 64 + lane];
            acc[n] = __builtin_amdgcn_mfma_f32_16x16x32_bf16(a, b, acc[n], 0, 0, 0);
        }
    }

    #pragma unroll
    for (int n = 0; n < 8; ++n) {
        int col = (nhalf * 8 + n) * 16 + lcol;
        #pragma unroll
        for (int r = 0; r < 4; ++r) {
            int row = rowBase + mtile * 16 + quad * 4 + r;
            if (row < nrows) H[(size_t)row * D + col] = f2b(acc[n][r]);
        }
    }
}

// ---------- chunked aggregate: block b -> column chunk (b&7), node group (b>>3) ----------
// XCD-pinned column slabs: round-robin dispatch puts chunk c on XCD c, so each XCD's
// gather working set is a 50000 x 64 B slab (3.2 MB) that FITS its private 4 MB L2.
// (r3 counters: flat layout forced each XCD to re-fetch the full 25.6 MB H: 187 MB/dispatch.)
__device__ inline void fma8(uint4 p, float nw, float* a) {
    a[0] = fmaf(b2f((unsigned short)(p.x & 0xffffu)), nw, a[0]);
    a[1] = fmaf(b2f((unsigned short)(p.x >> 16)),     nw, a[1]);
    a[2] = fmaf(b2f((unsigned short)(p.y & 0xffffu)), nw, a[2]);
    a[3] = fmaf(b2f((unsigned short)(p.y >> 16)),     nw, a[3]);
    a[4] = fmaf(b2f((unsigned short)(p.z & 0xffffu)), nw, a[4]);
    a[5] = fmaf(b2f((unsigned short)(p.z >> 16)),     nw, a[5]);
    a[6] = fmaf(b2f((unsigned short)(p.w & 0xffffu)), nw, a[6]);
    a[7] = fmaf(b2f((unsigned short)(p.w >> 16)),     nw, a[7]);
}

__global__ __launch_bounds__(256) void k_agg_chunk(const unsigned short* __restrict__ Hh,
                                                   const int* __restrict__ rowptr,
                                                   const int2* __restrict__ erec,
                                                   const float* __restrict__ dinv,
                                                   const float* __restrict__ b,
                                                   unsigned short* __restrict__ Xo,
                                                   int n, int relu) {
    int blk = blockIdx.x;
    int chunk = blk & 7;          // -> XCD (round-robin dispatch heuristic; perf-only)
    int grp = blk >> 3;
    int t = threadIdx.x;
    int lane4 = t & 3;
    int gid = t >> 2;             // 0..63 four-lane groups
    int cbase = chunk * 32 + lane4 * 8;   // this lane's 8 bf16 columns

    float4 b0 = *(const float4*)&b[cbase];
    float4 b1 = *(const float4*)&b[cbase + 4];

    int node0 = grp * NPB + gid * NPN;
    #pragma unroll
    for (int k = 0; k < NPN; ++k) {
        int node = node0 + k;
        if (node >= n) break;

        float dn = dinv[node];
        float self = dn * dn;

        float acc[8];
        acc[0] = b0.x; acc[1] = b0.y; acc[2] = b0.z; acc[3] = b0.w;
        acc[4] = b1.x; acc[5] = b1.y; acc[6] = b1.z; acc[7] = b1.w;
        {
            uint4 hp = *(const uint4*)&Hh[(size_t)node * D + cbase];
            fma8(hp, self, acc);
        }

        int beg = rowptr[node], end = rowptr[node + 1];
        int j = beg;
        for (; j + 3 < end; j += 4) {
            int2 rA = erec[j], rB = erec[j + 1], rC = erec[j + 2], rD = erec[j + 3];
            uint4 pA = *(const uint4*)&Hh[(size_t)rA.x * D + cbase];
            uint4 pB = *(const uint4*)&Hh[(size_t)rB.x * D + cbase];
            uint4 pC = *(const uint4*)&Hh[(size_t)rC.x * D + cbase];
            uint4 pD = *(const uint4*)&Hh[(size_t)rD.x * D + cbase];
            fma8(pA, __int_as_float(rA.y), acc);
            fma8(pB, __int_as_float(rB.y), acc);
            fma8(pC, __int_as_float(rC.y), acc);
            fma8(pD, __int_as_float(rD.y), acc);
        }
        for (; j < end; ++j) {
            int2 rA = erec[j];
            uint4 pA = *(const uint4*)&Hh[(size_t)rA.x * D + cbase];
            fma8(pA, __int_as_float(rA.y), acc);
        }
        if (relu) {
            #pragma unroll
            for (int i = 0; i < 8; ++i) acc[i] = fmaxf(acc[i], 0.f);
        }
        uint4 pk;
        pk.x = (unsigned int)f2b(acc[0]) | ((unsigned int)f2b(acc[1]) << 16);
        pk.y = (unsigned int)f2b(acc[2]) | ((unsigned int)f2b(acc[3]) << 16);
        pk.z = (unsigned int)f2b(acc[4]) | ((unsigned int)f2b(acc[5]) << 16);
        pk.w = (unsigned int)f2b(acc[6]) | ((unsigned int)f2b(acc[7]) << 16);
        *(uint4*)&Xo[(size_t)node * D + cbase] = pk;
    }
}

// ---------- link predictor v2 (VERIFIED 60.5 us): 64 q/block, block-shared product tile ----------
// Products computed ONCE per block; M=64 halves B L2-traffic per query.
// NOTE: async global_load_lds gather variant measured 84.5 us (r2) — do NOT reintroduce.
__global__ __launch_bounds__(256, 4) void k_linkpred(const int* __restrict__ u, const int* __restrict__ v,
                                                     const unsigned short* __restrict__ X16,
                                                     const unsigned short* __restrict__ Bpack,
                                                     const float* __restrict__ P1b,
                                                     const float* __restrict__ P2w, const float* __restrict__ P2b,
                                                     float* __restrict__ out, int Q) {
    __shared__ unsigned short P[64 * PPITCH];   // 33,792 B product tile (MFMA-A layout)
    __shared__ float red[4][64];

    int t = threadIdx.x;
    int q0 = blockIdx.x * 64;

    // ---- stage 0: gather endpoint rows from global, multiply, write product tile ----
    // 4 threads per query; thread (q, c0) handles chunks c = c0 + 4*i (16B each), i = 0..7.
    {
        int q = t >> 2, c0 = t & 3;
        int qq = q0 + q;
        int qc = (qq < Q) ? qq : 0;
        const uint4* ur = (const uint4*)(X16 + (size_t)u[qc] * D);
        const uint4* vr = (const uint4*)(X16 + (size_t)v[qc] * D);
        unsigned short* prow = &P[q * PPITCH];
        #pragma unroll
        for (int i = 0; i < 8; ++i) {
            int c = c0 + 4 * i;
            uint4 a = ur[c];
            uint4 b = vr[c];
            uint4 p;
            p.x = bmul2t(a.x, b.x);
            p.y = bmul2t(a.y, b.y);
            p.z = bmul2t(a.z, b.z);
            p.w = bmul2t(a.w, b.w);
            *(uint4*)(prow + c * 8) = p;
        }
    }
    __syncthreads();

    // ---- stage 1: MFMA, 4 m-tiles x 4 n-tiles per wave ----
    int w = t >> 6, lane = t & 63;
    int quad = lane >> 4, lcol = lane & 15;

    frag_cd acc[4][4];
    #pragma unroll
    for (int m = 0; m < 4; ++m)
        #pragma unroll
        for (int jn = 0; jn < 4; ++jn) acc[m][jn] = (frag_cd){0.f, 0.f, 0.f, 0.f};

    const frag_ab* bp = (const frag_ab*)Bpack;
    for (int kt = 0; kt < 8; ++kt) {
        frag_ab a[4];
        #pragma unroll
        for (int m = 0; m < 4; ++m)
            a[m] = *(const frag_ab*)&P[(m * 16 + lcol) * PPITCH + kt * 32 + quad * 8];
        #pragma unroll
        for (int jn = 0; jn < 4; ++jn) {
            frag_ab b = bp[((w * 4 + jn) * 8 + kt) * 64 + lane];
            #pragma unroll
            for (int m = 0; m < 4; ++m)
                acc[m][jn] = __builtin_amdgcn_mfma_f32_16x16x32_bf16(a[m], b, acc[m][jn], 0, 0, 0);
        }
    }

    // ---- epilogue: relu(H+b1) . P2w, partial over this wave's 4 ntiles ----
    float part[4][4] = {{0.f,0.f,0.f,0.f},{0.f,0.f,0.f,0.f},{0.f,0.f,0.f,0.f},{0.f,0.f,0.f,0.f}};
    #pragma unroll
    for (int jn = 0; jn < 4; ++jn) {
        int col = (w * 4 + jn) * 16 + lcol;
        float bb = P1b[col];
        float pw = P2w[col];
        #pragma unroll
        for (int m = 0; m < 4; ++m)
            #pragma unroll
            for (int r = 0; r < 4; ++r)
                part[m][r] = fmaf(fmaxf(acc[m][jn][r] + bb, 0.f), pw, part[m][r]);
    }
    #pragma unroll
    for (int m = 0; m < 4; ++m)
        #pragma unroll
        for (int r = 0; r < 4; ++r) {
            float s = part[m][r];
            s += __shfl_down(s, 8);
            s += __shfl_down(s, 4);
            s += __shfl_down(s, 2);
            s += __shfl_down(s, 1);
            part[m][r] = s;
        }
    if (lcol == 0) {
        #pragma unroll
        for (int m = 0; m < 4; ++m)
            #pragma unroll
            for (int r = 0; r < 4; ++r)
                red[w][m * 16 + quad * 4 + r] = part[m][r];
    }
    __syncthreads();

    if (t < 64) {
        int qq = q0 + t;
        if (qq < Q) {
            float s = red[0][t] + red[1][t] + red[2][t] + red[3][t] + P2b[0];
            out[qq] = 1.0f / (1.0f + expf(-s));
        }
    }
}

extern "C" void kernel_launch(void* const* d_in, const int* in_sizes, int n_in,
                              void* d_out, int out_size, void* d_ws, size_t ws_size,
                              hipStream_t stream) {
    const int*   edge_index = (const int*)d_in[0];
    const int*   edges      = (const int*)d_in[1];
    const float* emb        = (const float*)d_in[2];
    const float* W1         = (const float*)d_in[3];
    const float* b1         = (const float*)d_in[4];
    const float* W2         = (const float*)d_in[5];
    const float* b2         = (const float*)d_in[6];
    const float* P1w        = (const float*)d_in[7];
    const float* P1b        = (const float*)d_in[8];
    const float* P2w        = (const float*)d_in[9];
    const float* P2b        = (const float*)d_in[10];

    int E  = in_sizes[0] / 2;
    int Q  = in_sizes[1] / 2;
    int Nn = in_sizes[2] / D;

    const int* rowp = edge_index;
    const int* colp = edge_index + E;
    const int* uq   = edges;
    const int* vq   = edges + Q;
    float* out = (float*)d_out;

    // ---- workspace layout ----
    char* ws = (char*)d_ws;
    size_t off = 0;
    auto alloc = [&](size_t bytes) -> char* {
        char* p = ws + off;
        off = (off + bytes + 255) & ~(size_t)255;
        return p;
    };
    float*          dinv   = (float*)alloc((size_t)Nn * 4);
    int*            rowptr = (int*)  alloc(((size_t)Nn + 1) * 4);
    int2*           erec   = (int2*) alloc((size_t)E * 8);            // {col, dinv[r]*dinv[c]}
    unsigned short* BpW1   = (unsigned short*)alloc(65536 * 2);
    unsigned short* BpW2   = (unsigned short*)alloc(65536 * 2);
    unsigned short* BpP1   = (unsigned short*)alloc(65536 * 2);
    unsigned short* hbuf   = (unsigned short*)alloc((size_t)Nn * D * 2);  // bf16
    unsigned short* xbuf   = (unsigned short*)alloc((size_t)Nn * D * 2);  // bf16

    // CSR temporaries aliased into xbuf (dead until first k_agg_chunk writes it)
    int* degi  = (int*)xbuf;
    int* fill  = degi + Nn;
    int* bsums = degi + 2 * Nn;

    int nb;
    int nscan = (Nn + SCAN_CHUNK - 1) / SCAN_CHUNK;
    int ngrp  = (Nn + NPB - 1) / NPB;

    // CSR build
    nb = (2 * Nn + 255) / 256; k_zero_int<<<nb, 256, 0, stream>>>(degi, 2 * Nn);
    nb = (E + 255) / 256;      k_count_int<<<nb, 256, 0, stream>>>(rowp, degi, E);
    k_scan_block<<<nscan, 256, 0, stream>>>(degi, rowptr, bsums, Nn);
    k_scan_bsums<<<1, 256, 0, stream>>>(bsums, nscan);
    nb = (Nn + 255) / 256;     k_scan_add_dinv<<<nb, 256, 0, stream>>>(rowptr, bsums, degi, dinv, Nn, E);
    nb = (E + 255) / 256;      k_bucket<<<nb, 256, 0, stream>>>(rowp, colp, rowptr, fill, erec, dinv, E);

    // pack all three weights for MFMA B operand (one launch)
    k_packB3<<<768, 256, 0, stream>>>(W1, W2, P1w, BpW1, BpW2, BpP1);

    // conv1: h = emb @ W1 (MFMA, fp32 A) ; x1 = relu(norm-agg(h) + b1)  [bf16]
    nb = (Nn + 31) / 32; k_gemm_mfma<<<nb, 256, 0, stream>>>((const void*)emb, 1, BpW1, hbuf, Nn);
    k_agg_chunk<<<ngrp * 8, 256, 0, stream>>>(hbuf, rowptr, erec, dinv, b1, xbuf, Nn, 1);

    // conv2: h = x1 @ W2 (MFMA, bf16 A) ; x2 = norm-agg(h) + b2          [bf16]
    nb = (Nn + 31) / 32; k_gemm_mfma<<<nb, 256, 0, stream>>>((const void*)xbuf, 0, BpW2, hbuf, Nn);
    k_agg_chunk<<<ngrp * 8, 256, 0, stream>>>(hbuf, rowptr, erec, dinv, b2, xbuf, Nn, 0);

    // link predictor v2 (verified 60.5 us): 64 queries/block, block-shared product tile
    nb = (Q + 63) / 64;  k_linkpred<<<nb, 256, 0, stream>>>(uq, vq, xbuf, BpP1, P1b, P2w, P2b, out, Q);
}

// Round 5
// 429.312 us; speedup vs baseline: 1.2194x; 1.2194x over previous
//
#include <hip/hip_runtime.h>
#include <math.h>

#define D 256
#define SCAN_CHUNK 1024
#define GPITCH 264    // bf16 LDS pitch for MFMA A tiles (pad 8) — verified pattern r3-r9
#define PPITCH 264    // product tile pitch for linkpred (same verified MFMA-A pattern)

typedef __attribute__((ext_vector_type(8))) short frag_ab;   // 8 bf16
typedef __attribute__((ext_vector_type(4))) float frag_cd;   // 4 fp32

__device__ inline unsigned short f2b(float f) {
    unsigned int u = __float_as_uint(f);
    u += 0x7fffu + ((u >> 16) & 1u);
    return (unsigned short)(u >> 16);
}
__device__ inline float b2f(unsigned short h) {
    return __uint_as_float(((unsigned int)h) << 16);
}
// elementwise product of two packed bf16 pairs -> packed bf16 pair (TRUNCATING, 7 VALU ops)
__device__ inline unsigned int bmul2t(unsigned int a, unsigned int b) {
    float a0 = __uint_as_float(a << 16);
    float a1 = __uint_as_float(a & 0xffff0000u);
    float b0 = __uint_as_float(b << 16);
    float b1 = __uint_as_float(b & 0xffff0000u);
    float p0 = a0 * b0, p1 = a1 * b1;
    // out = (hi16(p1) << 16) | hi16(p0)
    return __builtin_amdgcn_perm(__float_as_uint(p1), __float_as_uint(p0), 0x07060302);
}

// ---------- zero int buffer ----------
__global__ void k_zero_int(int* p, int n) {
    int i = blockIdx.x * 256 + threadIdx.x;
    if (i < n) p[i] = 0;
}

// ---------- int degree count ----------
__global__ void k_count_int(const int* __restrict__ row, int* deg, int E) {
    int e = blockIdx.x * 256 + threadIdx.x;
    if (e < E) atomicAdd(&deg[row[e]], 1);
}

// ---------- prefix scan (2 stages now); excl written into rowptr ----------
__global__ __launch_bounds__(256) void k_scan_block(const int* __restrict__ deg, int* __restrict__ excl,
                                                    int* __restrict__ bsums, int n) {
    __shared__ int s[256];
    int blk = blockIdx.x, t = threadIdx.x;
    int base = blk * SCAN_CHUNK + t * 4;
    int v0 = (base + 0 < n) ? deg[base + 0] : 0;
    int v1 = (base + 1 < n) ? deg[base + 1] : 0;
    int v2 = (base + 2 < n) ? deg[base + 2] : 0;
    int v3 = (base + 3 < n) ? deg[base + 3] : 0;
    int tsum = v0 + v1 + v2 + v3;
    s[t] = tsum;
    __syncthreads();
    for (int off = 1; off < 256; off <<= 1) {
        int x = (t >= off) ? s[t - off] : 0;
        __syncthreads();
        s[t] += x;
        __syncthreads();
    }
    int run = s[t] - tsum;
    if (t == 255) bsums[blk] = s[255];
    if (base + 0 < n) excl[base + 0] = run;
    run += v0;
    if (base + 1 < n) excl[base + 1] = run;
    run += v1;
    if (base + 2 < n) excl[base + 2] = run;
    run += v2;
    if (base + 3 < n) excl[base + 3] = run;
}

// fused (r5): every block locally exclusive-scans bsums (nb<=256), then
// rowptr[i] += scanned[i/SCAN_CHUNK] AND dinv[i] = rsqrt(deg[i]+1).
// Removes the separate k_scan_bsums launch (one fewer kernel + gap).
__global__ __launch_bounds__(256) void k_scan_add_dinv(int* __restrict__ rowptr, const int* __restrict__ bsums,
                                                       const int* __restrict__ deg, float* __restrict__ dinv,
                                                       int n, int total, int nb) {
    __shared__ int s[256];
    int t = threadIdx.x;
    int v = (t < nb) ? bsums[t] : 0;
    s[t] = v;
    __syncthreads();
    for (int off = 1; off < 256; off <<= 1) {
        int x = (t >= off) ? s[t - off] : 0;
        __syncthreads();
        s[t] += x;
        __syncthreads();
    }
    int excl = s[t] - v;
    __syncthreads();
    s[t] = excl;
    __syncthreads();
    int i = blockIdx.x * 256 + t;
    if (i < n) {
        rowptr[i] += s[i >> 10];   // SCAN_CHUNK = 1024
        dinv[i] = rsqrtf((float)(deg[i] + 1));
    }
    if (i == 0) rowptr[n] = total;
}

// ---------- bucket edges into CSR (r1-verified form: plain col index) ----------
__global__ void k_bucket(const int* __restrict__ row, const int* __restrict__ col,
                         const int* __restrict__ rowptr, int* __restrict__ fill,
                         int* __restrict__ ebuf, int E) {
    int e = blockIdx.x * 256 + threadIdx.x;
    if (e >= E) return;
    int r = row[e];
    int pos = atomicAdd(&fill[r], 1);
    ebuf[rowptr[r] + pos] = col[e];
}

// ---------- pack three fp32 [k][n] weights into MFMA B-fragment order (bf16) ----------
__global__ void k_packB3(const float* __restrict__ Wa, const float* __restrict__ Wb,
                         const float* __restrict__ Wc,
                         unsigned short* __restrict__ Ba, unsigned short* __restrict__ Bb,
                         unsigned short* __restrict__ Bc) {
    int which = blockIdx.x >> 8;
    int i = (blockIdx.x & 255) * 256 + threadIdx.x;   // 65536 per weight
    const float* W = (which == 0) ? Wa : (which == 1) ? Wb : Wc;
    unsigned short* Bp = (which == 0) ? Ba : (which == 1) ? Bb : Bc;
    int ntile = i >> 12;
    int kt = (i >> 9) & 7;
    int lane = (i >> 3) & 63;
    int j = i & 7;
    int k = kt * 32 + (lane >> 4) * 8 + j;
    int n = ntile * 16 + (lane & 15);
    Bp[i] = f2b(W[k * D + n]);
}

// ---------- MFMA GEMM v2: 64 rows/block, 16B staging loads, acc[2][8] per wave ----------
// r5 experiment: halves block count (782 vs 1563) and per-row B traffic; A-frag reused 8x.
__global__ __launch_bounds__(256) void k_gemm_mfma(const void* __restrict__ X, int xIsF32,
                                                   const unsigned short* __restrict__ Bpack,
                                                   unsigned short* __restrict__ H, int nrows) {
    __shared__ unsigned short As[64 * GPITCH];   // 33,792 B
    int t = threadIdx.x;
    int rowBase = blockIdx.x * 64;

    // staging: 4 threads per row; 16B global loads
    {
        int q = t >> 2, c0 = t & 3;
        int r = rowBase + q;
        if (xIsF32) {
            const uint4* xr = (const uint4*)((const float*)X + (size_t)r * D);
            #pragma unroll
            for (int i = 0; i < 16; ++i) {
                int c = c0 + 4 * i;              // 16B chunk = 4 fp32 = cols 4c..4c+3
                uint4 val = make_uint4(0, 0, 0, 0);
                if (r < nrows) val = xr[c];
                unsigned int lo = (unsigned int)f2b(__uint_as_float(val.x))
                                | ((unsigned int)f2b(__uint_as_float(val.y)) << 16);
                unsigned int hi = (unsigned int)f2b(__uint_as_float(val.z))
                                | ((unsigned int)f2b(__uint_as_float(val.w)) << 16);
                *(uint2*)&As[q * GPITCH + c * 4] = make_uint2(lo, hi);
            }
        } else {
            const uint4* xr = (const uint4*)((const unsigned short*)X + (size_t)r * D);
            #pragma unroll
            for (int i = 0; i < 8; ++i) {
                int c = c0 + 4 * i;              // 16B chunk = 8 bf16
                uint4 val = make_uint4(0, 0, 0, 0);
                if (r < nrows) val = xr[c];
                *(uint4*)&As[q * GPITCH + c * 8] = val;
            }
        }
    }
    __syncthreads();

    int w = t >> 6, lane = t & 63;
    int mpair = w >> 1;        // rows mpair*32 .. +31 (2 mtiles)
    int nhalf = w & 1;         // cols nhalf*128 .. +127 (8 ntiles)
    int quad = lane >> 4, lcol = lane & 15;

    frag_cd acc[2][8];
    #pragma unroll
    for (int m = 0; m < 2; ++m)
        #pragma unroll
        for (int n = 0; n < 8; ++n) acc[m][n] = (frag_cd){0.f, 0.f, 0.f, 0.f};

    const frag_ab* bp = (const frag_ab*)Bpack;
    for (int kt = 0; kt < 8; ++kt) {
        frag_ab a[2];
        #pragma unroll
        for (int m = 0; m < 2; ++m)
            a[m] = *(const frag_ab*)&As[((mpair * 2 + m) * 16 + lcol) * GPITCH + kt * 32 + quad * 8];
        #pragma unroll
        for (int n = 0; n < 8; ++n) {
            frag_ab b = bp[((nhalf * 8 + n) * 8 + kt) * 64 + lane];
            acc[0][n] = __builtin_amdgcn_mfma_f32_16x16x32_bf16(a[0], b, acc[0][n], 0, 0, 0);
            acc[1][n] = __builtin_amdgcn_mfma_f32_16x16x32_bf16(a[1], b, acc[1][n], 0, 0, 0);
        }
    }

    #pragma unroll
    for (int n = 0; n < 8; ++n) {
        int col = (nhalf * 8 + n) * 16 + lcol;
        #pragma unroll
        for (int m = 0; m < 2; ++m)
            #pragma unroll
            for (int r = 0; r < 4; ++r) {
                int row = rowBase + (mpair * 2 + m) * 16 + quad * 4 + r;
                if (row < nrows) H[(size_t)row * D + col] = f2b(acc[m][n][r]);
            }
    }
}

// ---------- aggregate by gather (r1-VERIFIED ~60.2 us): 2 nodes/wave, 32 lanes (16B) per node ----
// Post-mortems: 8-deep batching (r3) neutral; chunked/XCD-pinned (r4) regressed 2x
// (128B-line waste + slab > L2 + 8x edge-list re-read). Flat 4-deep is the keeper.
__device__ inline void fma8(uint4 p, float nw, float* a) {
    a[0] = fmaf(b2f((unsigned short)(p.x & 0xffffu)), nw, a[0]);
    a[1] = fmaf(b2f((unsigned short)(p.x >> 16)),     nw, a[1]);
    a[2] = fmaf(b2f((unsigned short)(p.y & 0xffffu)), nw, a[2]);
    a[3] = fmaf(b2f((unsigned short)(p.y >> 16)),     nw, a[3]);
    a[4] = fmaf(b2f((unsigned short)(p.z & 0xffffu)), nw, a[4]);
    a[5] = fmaf(b2f((unsigned short)(p.z >> 16)),     nw, a[5]);
    a[6] = fmaf(b2f((unsigned short)(p.w & 0xffffu)), nw, a[6]);
    a[7] = fmaf(b2f((unsigned short)(p.w >> 16)),     nw, a[7]);
}

__global__ __launch_bounds__(256) void k_agg(const unsigned short* __restrict__ Hh,
                                             const int* __restrict__ rowptr, const int* __restrict__ ebuf,
                                             const float* __restrict__ dinv, const float* __restrict__ b,
                                             unsigned short* __restrict__ Xo, int n, int relu) {
    int w = threadIdx.x >> 6, lane = threadIdx.x & 63;
    int half = lane >> 5, sub = lane & 31;
    int node = (blockIdx.x * 4 + w) * 2 + half;
    if (node >= n) return;
    int c8 = sub * 8;

    float dn = dinv[node];
    float self = dn * dn;

    float acc[8];
    {
        uint4 hp = *(const uint4*)&Hh[(size_t)node * D + c8];
        float4 b0 = *(const float4*)&b[c8];
        float4 b1 = *(const float4*)&b[c8 + 4];
        acc[0] = b0.x; acc[1] = b0.y; acc[2] = b0.z; acc[3] = b0.w;
        acc[4] = b1.x; acc[5] = b1.y; acc[6] = b1.z; acc[7] = b1.w;
        fma8(hp, self, acc);
    }

    int beg = rowptr[node], end = rowptr[node + 1];
    int j = beg;
    for (; j + 3 < end; j += 4) {
        int cA = ebuf[j], cB = ebuf[j + 1], cC = ebuf[j + 2], cD = ebuf[j + 3];
        float nA = dn * dinv[cA], nB = dn * dinv[cB], nC = dn * dinv[cC], nD = dn * dinv[cD];
        uint4 pA = *(const uint4*)&Hh[(size_t)cA * D + c8];
        uint4 pB = *(const uint4*)&Hh[(size_t)cB * D + c8];
        uint4 pC = *(const uint4*)&Hh[(size_t)cC * D + c8];
        uint4 pD = *(const uint4*)&Hh[(size_t)cD * D + c8];
        fma8(pA, nA, acc);
        fma8(pB, nB, acc);
        fma8(pC, nC, acc);
        fma8(pD, nD, acc);
    }
    for (; j < end; ++j) {
        int cA = ebuf[j];
        uint4 pA = *(const uint4*)&Hh[(size_t)cA * D + c8];
        fma8(pA, dn * dinv[cA], acc);
    }
    if (relu) {
        #pragma unroll
        for (int i = 0; i < 8; ++i) acc[i] = fmaxf(acc[i], 0.f);
    }
    uint4 pk;
    pk.x = (unsigned int)f2b(acc[0]) | ((unsigned int)f2b(acc[1]) << 16);
    pk.y = (unsigned int)f2b(acc[2]) | ((unsigned int)f2b(acc[3]) << 16);
    pk.z = (unsigned int)f2b(acc[4]) | ((unsigned int)f2b(acc[5]) << 16);
    pk.w = (unsigned int)f2b(acc[6]) | ((unsigned int)f2b(acc[7]) << 16);
    *(uint4*)&Xo[(size_t)node * D + c8] = pk;
}

// ---------- link predictor v2 (VERIFIED 60.5 us): 64 q/block, block-shared product tile ----------
// Products computed ONCE per block; M=64 halves B L2-traffic per query.
// NOTE: async global_load_lds gather variant measured 84.5 us (r2) — do NOT reintroduce.
__global__ __launch_bounds__(256, 4) void k_linkpred(const int* __restrict__ u, const int* __restrict__ v,
                                                     const unsigned short* __restrict__ X16,
                                                     const unsigned short* __restrict__ Bpack,
                                                     const float* __restrict__ P1b,
                                                     const float* __restrict__ P2w, const float* __restrict__ P2b,
                                                     float* __restrict__ out, int Q) {
    __shared__ unsigned short P[64 * PPITCH];   // 33,792 B product tile (MFMA-A layout)
    __shared__ float red[4][64];

    int t = threadIdx.x;
    int q0 = blockIdx.x * 64;

    // ---- stage 0: gather endpoint rows from global, multiply, write product tile ----
    {
        int q = t >> 2, c0 = t & 3;
        int qq = q0 + q;
        int qc = (qq < Q) ? qq : 0;
        const uint4* ur = (const uint4*)(X16 + (size_t)u[qc] * D);
        const uint4* vr = (const uint4*)(X16 + (size_t)v[qc] * D);
        unsigned short* prow = &P[q * PPITCH];
        #pragma unroll
        for (int i = 0; i < 8; ++i) {
            int c = c0 + 4 * i;
            uint4 a = ur[c];
            uint4 b = vr[c];
            uint4 p;
            p.x = bmul2t(a.x, b.x);
            p.y = bmul2t(a.y, b.y);
            p.z = bmul2t(a.z, b.z);
            p.w = bmul2t(a.w, b.w);
            *(uint4*)(prow + c * 8) = p;
        }
    }
    __syncthreads();

    // ---- stage 1: MFMA, 4 m-tiles x 4 n-tiles per wave ----
    int w = t >> 6, lane = t & 63;
    int quad = lane >> 4, lcol = lane & 15;

    frag_cd acc[4][4];
    #pragma unroll
    for (int m = 0; m < 4; ++m)
        #pragma unroll
        for (int jn = 0; jn < 4; ++jn) acc[m][jn] = (frag_cd){0.f, 0.f, 0.f, 0.f};

    const frag_ab* bp = (const frag_ab*)Bpack;
    for (int kt = 0; kt < 8; ++kt) {
        frag_ab a[4];
        #pragma unroll
        for (int m = 0; m < 4; ++m)
            a[m] = *(const frag_ab*)&P[(m * 16 + lcol) * PPITCH + kt * 32 + quad * 8];
        #pragma unroll
        for (int jn = 0; jn < 4; ++jn) {
            frag_ab b = bp[((w * 4 + jn) * 8 + kt) * 64 + lane];
            #pragma unroll
            for (int m = 0; m < 4; ++m)
                acc[m][jn] = __builtin_amdgcn_mfma_f32_16x16x32_bf16(a[m], b, acc[m][jn], 0, 0, 0);
        }
    }

    // ---- epilogue: relu(H+b1) . P2w, partial over this wave's 4 ntiles ----
    float part[4][4] = {{0.f,0.f,0.f,0.f},{0.f,0.f,0.f,0.f},{0.f,0.f,0.f,0.f},{0.f,0.f,0.f,0.f}};
    #pragma unroll
    for (int jn = 0; jn < 4; ++jn) {
        int col = (w * 4 + jn) * 16 + lcol;
        float bb = P1b[col];
        float pw = P2w[col];
        #pragma unroll
        for (int m = 0; m < 4; ++m)
            #pragma unroll
            for (int r = 0; r < 4; ++r)
                part[m][r] = fmaf(fmaxf(acc[m][jn][r] + bb, 0.f), pw, part[m][r]);
    }
    #pragma unroll
    for (int m = 0; m < 4; ++m)
        #pragma unroll
        for (int r = 0; r < 4; ++r) {
            float s = part[m][r];
            s += __shfl_down(s, 8);
            s += __shfl_down(s, 4);
            s += __shfl_down(s, 2);
            s += __shfl_down(s, 1);
            part[m][r] = s;
        }
    if (lcol == 0) {
        #pragma unroll
        for (int m = 0; m < 4; ++m)
            #pragma unroll
            for (int r = 0; r < 4; ++r)
                red[w][m * 16 + quad * 4 + r] = part[m][r];
    }
    __syncthreads();

    if (t < 64) {
        int qq = q0 + t;
        if (qq < Q) {
            float s = red[0][t] + red[1][t] + red[2][t] + red[3][t] + P2b[0];
            out[qq] = 1.0f / (1.0f + expf(-s));
        }
    }
}

extern "C" void kernel_launch(void* const* d_in, const int* in_sizes, int n_in,
                              void* d_out, int out_size, void* d_ws, size_t ws_size,
                              hipStream_t stream) {
    const int*   edge_index = (const int*)d_in[0];
    const int*   edges      = (const int*)d_in[1];
    const float* emb        = (const float*)d_in[2];
    const float* W1         = (const float*)d_in[3];
    const float* b1         = (const float*)d_in[4];
    const float* W2         = (const float*)d_in[5];
    const float* b2         = (const float*)d_in[6];
    const float* P1w        = (const float*)d_in[7];
    const float* P1b        = (const float*)d_in[8];
    const float* P2w        = (const float*)d_in[9];
    const float* P2b        = (const float*)d_in[10];

    int E  = in_sizes[0] / 2;
    int Q  = in_sizes[1] / 2;
    int Nn = in_sizes[2] / D;

    const int* rowp = edge_index;
    const int* colp = edge_index + E;
    const int* uq   = edges;
    const int* vq   = edges + Q;
    float* out = (float*)d_out;

    // ---- workspace layout ----
    char* ws = (char*)d_ws;
    size_t off = 0;
    auto alloc = [&](size_t bytes) -> char* {
        char* p = ws + off;
        off = (off + bytes + 255) & ~(size_t)255;
        return p;
    };
    float*          dinv   = (float*)alloc((size_t)Nn * 4);
    int*            rowptr = (int*)  alloc(((size_t)Nn + 1) * 4);
    int*            ebuf   = (int*)  alloc((size_t)E * 4);
    unsigned short* BpW1   = (unsigned short*)alloc(65536 * 2);
    unsigned short* BpW2   = (unsigned short*)alloc(65536 * 2);
    unsigned short* BpP1   = (unsigned short*)alloc(65536 * 2);
    unsigned short* hbuf   = (unsigned short*)alloc((size_t)Nn * D * 2);  // bf16
    unsigned short* xbuf   = (unsigned short*)alloc((size_t)Nn * D * 2);  // bf16

    // CSR temporaries aliased into xbuf (dead until first k_agg writes it)
    int* degi  = (int*)xbuf;
    int* fill  = degi + Nn;
    int* bsums = degi + 2 * Nn;

    int nb;
    int nscan = (Nn + SCAN_CHUNK - 1) / SCAN_CHUNK;

    // CSR build (5 kernels; bsums scan folded into k_scan_add_dinv)
    nb = (2 * Nn + 255) / 256; k_zero_int<<<nb, 256, 0, stream>>>(degi, 2 * Nn);
    nb = (E + 255) / 256;      k_count_int<<<nb, 256, 0, stream>>>(rowp, degi, E);
    k_scan_block<<<nscan, 256, 0, stream>>>(degi, rowptr, bsums, Nn);
    nb = (Nn + 255) / 256;     k_scan_add_dinv<<<nb, 256, 0, stream>>>(rowptr, bsums, degi, dinv, Nn, E, nscan);
    nb = (E + 255) / 256;      k_bucket<<<nb, 256, 0, stream>>>(rowp, colp, rowptr, fill, ebuf, E);

    // pack all three weights for MFMA B operand (one launch)
    k_packB3<<<768, 256, 0, stream>>>(W1, W2, P1w, BpW1, BpW2, BpP1);

    // conv1: h = emb @ W1 (MFMA, fp32 A) ; x1 = relu(norm-agg(h) + b1)  [bf16]
    nb = (Nn + 63) / 64; k_gemm_mfma<<<nb, 256, 0, stream>>>((const void*)emb, 1, BpW1, hbuf, Nn);
    nb = (Nn + 7) / 8;   k_agg<<<nb, 256, 0, stream>>>(hbuf, rowptr, ebuf, dinv, b1, xbuf, Nn, 1);

    // conv2: h = x1 @ W2 (MFMA, bf16 A) ; x2 = norm-agg(h) + b2          [bf16]
    nb = (Nn + 63) / 64; k_gemm_mfma<<<nb, 256, 0, stream>>>((const void*)xbuf, 0, BpW2, hbuf, Nn);
    nb = (Nn + 7) / 8;   k_agg<<<nb, 256, 0, stream>>>(hbuf, rowptr, ebuf, dinv, b2, xbuf, Nn, 0);

    // link predictor v2 (verified 60.5 us): 64 queries/block, block-shared product tile
    nb = (Q + 63) / 64;  k_linkpred<<<nb, 256, 0, stream>>>(uq, vq, xbuf, BpP1, P1b, P2w, P2b, out, Q);
}

// Round 6
// 402.807 us; speedup vs baseline: 1.2996x; 1.0658x over previous
//
#include <hip/hip_runtime.h>
#include <math.h>

#define D 256
#define SCAN_CHUNK 1024
#define GPITCH 264    // bf16 LDS pitch for MFMA A tiles (pad 8) — verified pattern r3-r9
#define PPITCH 264    // product tile pitch for linkpred (same verified MFMA-A pattern)

typedef __attribute__((ext_vector_type(8))) short frag_ab;   // 8 bf16
typedef __attribute__((ext_vector_type(4))) float frag_cd;   // 4 fp32

__device__ inline unsigned short f2b(float f) {
    unsigned int u = __float_as_uint(f);
    u += 0x7fffu + ((u >> 16) & 1u);
    return (unsigned short)(u >> 16);
}
__device__ inline float b2f(unsigned short h) {
    return __uint_as_float(((unsigned int)h) << 16);
}
// elementwise product of two packed bf16 pairs -> packed bf16 pair (TRUNCATING, 7 VALU ops)
__device__ inline unsigned int bmul2t(unsigned int a, unsigned int b) {
    float a0 = __uint_as_float(a << 16);
    float a1 = __uint_as_float(a & 0xffff0000u);
    float b0 = __uint_as_float(b << 16);
    float b1 = __uint_as_float(b & 0xffff0000u);
    float p0 = a0 * b0, p1 = a1 * b1;
    // out = (hi16(p1) << 16) | hi16(p0)
    return __builtin_amdgcn_perm(__float_as_uint(p1), __float_as_uint(p0), 0x07060302);
}

// ---------- zero int buffer ----------
__global__ void k_zero_int(int* p, int n) {
    int i = blockIdx.x * 256 + threadIdx.x;
    if (i < n) p[i] = 0;
}

// ---------- int degree count ----------
__global__ void k_count_int(const int* __restrict__ row, int* deg, int E) {
    int e = blockIdx.x * 256 + threadIdx.x;
    if (e < E) atomicAdd(&deg[row[e]], 1);
}

// ---------- prefix scan (2 stages); excl written into rowptr ----------
__global__ __launch_bounds__(256) void k_scan_block(const int* __restrict__ deg, int* __restrict__ excl,
                                                    int* __restrict__ bsums, int n) {
    __shared__ int s[256];
    int blk = blockIdx.x, t = threadIdx.x;
    int base = blk * SCAN_CHUNK + t * 4;
    int v0 = (base + 0 < n) ? deg[base + 0] : 0;
    int v1 = (base + 1 < n) ? deg[base + 1] : 0;
    int v2 = (base + 2 < n) ? deg[base + 2] : 0;
    int v3 = (base + 3 < n) ? deg[base + 3] : 0;
    int tsum = v0 + v1 + v2 + v3;
    s[t] = tsum;
    __syncthreads();
    for (int off = 1; off < 256; off <<= 1) {
        int x = (t >= off) ? s[t - off] : 0;
        __syncthreads();
        s[t] += x;
        __syncthreads();
    }
    int run = s[t] - tsum;
    if (t == 255) bsums[blk] = s[255];
    if (base + 0 < n) excl[base + 0] = run;
    run += v0;
    if (base + 1 < n) excl[base + 1] = run;
    run += v1;
    if (base + 2 < n) excl[base + 2] = run;
    run += v2;
    if (base + 3 < n) excl[base + 3] = run;
}

// fused: every block locally exclusive-scans bsums (nb<=256), then
// rowptr[i] += scanned[i/SCAN_CHUNK] AND dinv[i] = rsqrt(deg[i]+1).
__global__ __launch_bounds__(256) void k_scan_add_dinv(int* __restrict__ rowptr, const int* __restrict__ bsums,
                                                       const int* __restrict__ deg, float* __restrict__ dinv,
                                                       int n, int total, int nb) {
    __shared__ int s[256];
    int t = threadIdx.x;
    int v = (t < nb) ? bsums[t] : 0;
    s[t] = v;
    __syncthreads();
    for (int off = 1; off < 256; off <<= 1) {
        int x = (t >= off) ? s[t - off] : 0;
        __syncthreads();
        s[t] += x;
        __syncthreads();
    }
    int excl = s[t] - v;
    __syncthreads();
    s[t] = excl;
    __syncthreads();
    int i = blockIdx.x * 256 + t;
    if (i < n) {
        rowptr[i] += s[i >> 10];   // SCAN_CHUNK = 1024
        dinv[i] = rsqrtf((float)(deg[i] + 1));
    }
    if (i == 0) rowptr[n] = total;
}

// ---------- bucket edges into CSR (r1-verified form: plain col index) ----------
__global__ void k_bucket(const int* __restrict__ row, const int* __restrict__ col,
                         const int* __restrict__ rowptr, int* __restrict__ fill,
                         int* __restrict__ ebuf, int E) {
    int e = blockIdx.x * 256 + threadIdx.x;
    if (e >= E) return;
    int r = row[e];
    int pos = atomicAdd(&fill[r], 1);
    ebuf[rowptr[r] + pos] = col[e];
}

// ---------- pack three fp32 [k][n] weights into MFMA B-fragment order (bf16) ----------
__global__ void k_packB3(const float* __restrict__ Wa, const float* __restrict__ Wb,
                         const float* __restrict__ Wc,
                         unsigned short* __restrict__ Ba, unsigned short* __restrict__ Bb,
                         unsigned short* __restrict__ Bc) {
    int which = blockIdx.x >> 8;
    int i = (blockIdx.x & 255) * 256 + threadIdx.x;   // 65536 per weight
    const float* W = (which == 0) ? Wa : (which == 1) ? Wb : Wc;
    unsigned short* Bp = (which == 0) ? Ba : (which == 1) ? Bb : Bc;
    int ntile = i >> 12;
    int kt = (i >> 9) & 7;
    int lane = (i >> 3) & 63;
    int j = i & 7;
    int k = kt * 32 + (lane >> 4) * 8 + j;
    int n = ntile * 16 + (lane & 15);
    Bp[i] = f2b(W[k * D + n]);
}

// ---------- MFMA GEMM (r1-verified 32-row structure, r6: vectorized staging) ----------
// Staging now uses 16B LDS writes / 16-32B global loads (4 iters/thread, was 16 iters
// of 4B writes). Values and LDS layout byte-identical to r1; MFMA loop untouched.
__global__ __launch_bounds__(256) void k_gemm_mfma(const void* __restrict__ X, int xIsF32,
                                                   const unsigned short* __restrict__ Bpack,
                                                   unsigned short* __restrict__ H, int nrows) {
    __shared__ unsigned short As[32 * GPITCH];
    int t = threadIdx.x;
    int rowBase = blockIdx.x * 32;

    {
        int q = t >> 3, c0 = t & 7;    // 8 threads per row, 32 rows
        int r = rowBase + q;
        if (xIsF32) {
            const uint4* xr = (const uint4*)((const float*)X + (size_t)r * D);
            #pragma unroll
            for (int i = 0; i < 4; ++i) {
                int c = c0 + 8 * i;    // 16B bf16 chunk (8 cols), needs 32B of fp32
                uint4 lo4 = make_uint4(0, 0, 0, 0), hi4 = make_uint4(0, 0, 0, 0);
                if (r < nrows) { lo4 = xr[2 * c]; hi4 = xr[2 * c + 1]; }
                uint4 o;
                o.x = (unsigned int)f2b(__uint_as_float(lo4.x)) | ((unsigned int)f2b(__uint_as_float(lo4.y)) << 16);
                o.y = (unsigned int)f2b(__uint_as_float(lo4.z)) | ((unsigned int)f2b(__uint_as_float(lo4.w)) << 16);
                o.z = (unsigned int)f2b(__uint_as_float(hi4.x)) | ((unsigned int)f2b(__uint_as_float(hi4.y)) << 16);
                o.w = (unsigned int)f2b(__uint_as_float(hi4.z)) | ((unsigned int)f2b(__uint_as_float(hi4.w)) << 16);
                *(uint4*)&As[q * GPITCH + c * 8] = o;
            }
        } else {
            const uint4* xr = (const uint4*)((const unsigned short*)X + (size_t)r * D);
            #pragma unroll
            for (int i = 0; i < 4; ++i) {
                int c = c0 + 8 * i;    // 16B chunk = 8 bf16
                uint4 v = make_uint4(0, 0, 0, 0);
                if (r < nrows) v = xr[c];
                *(uint4*)&As[q * GPITCH + c * 8] = v;
            }
        }
    }
    __syncthreads();

    int w = t >> 6, lane = t & 63;
    int mtile = w >> 1;
    int nhalf = w & 1;
    int quad = lane >> 4, lcol = lane & 15;

    frag_cd acc[8];
    #pragma unroll
    for (int n = 0; n < 8; ++n) acc[n] = (frag_cd){0.f, 0.f, 0.f, 0.f};

    const frag_ab* bp = (const frag_ab*)Bpack;
    for (int kt = 0; kt < 8; ++kt) {
        frag_ab a = *(const frag_ab*)&As[(mtile * 16 + lcol) * GPITCH + kt * 32 + quad * 8];
        #pragma unroll
        for (int n = 0; n < 8; ++n) {
            frag_ab b = bp[((nhalf * 8 + n) * 8 + kt) * 64 + lane];
            acc[n] = __builtin_amdgcn_mfma_f32_16x16x32_bf16(a, b, acc[n], 0, 0, 0);
        }
    }

    #pragma unroll
    for (int n = 0; n < 8; ++n) {
        int col = (nhalf * 8 + n) * 16 + lcol;
        #pragma unroll
        for (int r = 0; r < 4; ++r) {
            int row = rowBase + mtile * 16 + quad * 4 + r;
            if (row < nrows) H[(size_t)row * D + col] = f2b(acc[n][r]);
        }
    }
}

// ---------- aggregate by gather (VERIFIED ~59.2 us, 3x consistent): at random-line
// fabric ceiling (188 MB/dispatch ~= per-XCD compulsory distinct-row re-fetch).
// Post-mortems: 8-deep (r3) neutral; XCD-chunked (r4) 2x regression. DO NOT TOUCH.
__device__ inline void fma8(uint4 p, float nw, float* a) {
    a[0] = fmaf(b2f((unsigned short)(p.x & 0xffffu)), nw, a[0]);
    a[1] = fmaf(b2f((unsigned short)(p.x >> 16)),     nw, a[1]);
    a[2] = fmaf(b2f((unsigned short)(p.y & 0xffffu)), nw, a[2]);
    a[3] = fmaf(b2f((unsigned short)(p.y >> 16)),     nw, a[3]);
    a[4] = fmaf(b2f((unsigned short)(p.z & 0xffffu)), nw, a[4]);
    a[5] = fmaf(b2f((unsigned short)(p.z >> 16)),     nw, a[5]);
    a[6] = fmaf(b2f((unsigned short)(p.w & 0xffffu)), nw, a[6]);
    a[7] = fmaf(b2f((unsigned short)(p.w >> 16)),     nw, a[7]);
}

__global__ __launch_bounds__(256) void k_agg(const unsigned short* __restrict__ Hh,
                                             const int* __restrict__ rowptr, const int* __restrict__ ebuf,
                                             const float* __restrict__ dinv, const float* __restrict__ b,
                                             unsigned short* __restrict__ Xo, int n, int relu) {
    int w = threadIdx.x >> 6, lane = threadIdx.x & 63;
    int half = lane >> 5, sub = lane & 31;
    int node = (blockIdx.x * 4 + w) * 2 + half;
    if (node >= n) return;
    int c8 = sub * 8;

    float dn = dinv[node];
    float self = dn * dn;

    float acc[8];
    {
        uint4 hp = *(const uint4*)&Hh[(size_t)node * D + c8];
        float4 b0 = *(const float4*)&b[c8];
        float4 b1 = *(const float4*)&b[c8 + 4];
        acc[0] = b0.x; acc[1] = b0.y; acc[2] = b0.z; acc[3] = b0.w;
        acc[4] = b1.x; acc[5] = b1.y; acc[6] = b1.z; acc[7] = b1.w;
        fma8(hp, self, acc);
    }

    int beg = rowptr[node], end = rowptr[node + 1];
    int j = beg;
    for (; j + 3 < end; j += 4) {
        int cA = ebuf[j], cB = ebuf[j + 1], cC = ebuf[j + 2], cD = ebuf[j + 3];
        float nA = dn * dinv[cA], nB = dn * dinv[cB], nC = dn * dinv[cC], nD = dn * dinv[cD];
        uint4 pA = *(const uint4*)&Hh[(size_t)cA * D + c8];
        uint4 pB = *(const uint4*)&Hh[(size_t)cB * D + c8];
        uint4 pC = *(const uint4*)&Hh[(size_t)cC * D + c8];
        uint4 pD = *(const uint4*)&Hh[(size_t)cD * D + c8];
        fma8(pA, nA, acc);
        fma8(pB, nB, acc);
        fma8(pC, nC, acc);
        fma8(pD, nD, acc);
    }
    for (; j < end; ++j) {
        int cA = ebuf[j];
        uint4 pA = *(const uint4*)&Hh[(size_t)cA * D + c8];
        fma8(pA, dn * dinv[cA], acc);
    }
    if (relu) {
        #pragma unroll
        for (int i = 0; i < 8; ++i) acc[i] = fmaxf(acc[i], 0.f);
    }
    uint4 pk;
    pk.x = (unsigned int)f2b(acc[0]) | ((unsigned int)f2b(acc[1]) << 16);
    pk.y = (unsigned int)f2b(acc[2]) | ((unsigned int)f2b(acc[3]) << 16);
    pk.z = (unsigned int)f2b(acc[4]) | ((unsigned int)f2b(acc[5]) << 16);
    pk.w = (unsigned int)f2b(acc[6]) | ((unsigned int)f2b(acc[7]) << 16);
    *(uint4*)&Xo[(size_t)node * D + c8] = pk;
}

// ---------- link predictor v2 (VERIFIED 60.5 us): 64 q/block, block-shared product tile ----------
// Products computed ONCE per block; M=64 halves B L2-traffic per query.
// NOTE: async global_load_lds gather variant measured 84.5 us (r2) — do NOT reintroduce.
__global__ __launch_bounds__(256, 4) void k_linkpred(const int* __restrict__ u, const int* __restrict__ v,
                                                     const unsigned short* __restrict__ X16,
                                                     const unsigned short* __restrict__ Bpack,
                                                     const float* __restrict__ P1b,
                                                     const float* __restrict__ P2w, const float* __restrict__ P2b,
                                                     float* __restrict__ out, int Q) {
    __shared__ unsigned short P[64 * PPITCH];   // 33,792 B product tile (MFMA-A layout)
    __shared__ float red[4][64];

    int t = threadIdx.x;
    int q0 = blockIdx.x * 64;

    // ---- stage 0: gather endpoint rows from global, multiply, write product tile ----
    {
        int q = t >> 2, c0 = t & 3;
        int qq = q0 + q;
        int qc = (qq < Q) ? qq : 0;
        const uint4* ur = (const uint4*)(X16 + (size_t)u[qc] * D);
        const uint4* vr = (const uint4*)(X16 + (size_t)v[qc] * D);
        unsigned short* prow = &P[q * PPITCH];
        #pragma unroll
        for (int i = 0; i < 8; ++i) {
            int c = c0 + 4 * i;
            uint4 a = ur[c];
            uint4 b = vr[c];
            uint4 p;
            p.x = bmul2t(a.x, b.x);
            p.y = bmul2t(a.y, b.y);
            p.z = bmul2t(a.z, b.z);
            p.w = bmul2t(a.w, b.w);
            *(uint4*)(prow + c * 8) = p;
        }
    }
    __syncthreads();

    // ---- stage 1: MFMA, 4 m-tiles x 4 n-tiles per wave ----
    int w = t >> 6, lane = t & 63;
    int quad = lane >> 4, lcol = lane & 15;

    frag_cd acc[4][4];
    #pragma unroll
    for (int m = 0; m < 4; ++m)
        #pragma unroll
        for (int jn = 0; jn < 4; ++jn) acc[m][jn] = (frag_cd){0.f, 0.f, 0.f, 0.f};

    const frag_ab* bp = (const frag_ab*)Bpack;
    for (int kt = 0; kt < 8; ++kt) {
        frag_ab a[4];
        #pragma unroll
        for (int m = 0; m < 4; ++m)
            a[m] = *(const frag_ab*)&P[(m * 16 + lcol) * PPITCH + kt * 32 + quad * 8];
        #pragma unroll
        for (int jn = 0; jn < 4; ++jn) {
            frag_ab b = bp[((w * 4 + jn) * 8 + kt) * 64 + lane];
            #pragma unroll
            for (int m = 0; m < 4; ++m)
                acc[m][jn] = __builtin_amdgcn_mfma_f32_16x16x32_bf16(a[m], b, acc[m][jn], 0, 0, 0);
        }
    }

    // ---- epilogue: relu(H+b1) . P2w, partial over this wave's 4 ntiles ----
    float part[4][4] = {{0.f,0.f,0.f,0.f},{0.f,0.f,0.f,0.f},{0.f,0.f,0.f,0.f},{0.f,0.f,0.f,0.f}};
    #pragma unroll
    for (int jn = 0; jn < 4; ++jn) {
        int col = (w * 4 + jn) * 16 + lcol;
        float bb = P1b[col];
        float pw = P2w[col];
        #pragma unroll
        for (int m = 0; m < 4; ++m)
            #pragma unroll
            for (int r = 0; r < 4; ++r)
                part[m][r] = fmaf(fmaxf(acc[m][jn][r] + bb, 0.f), pw, part[m][r]);
    }
    #pragma unroll
    for (int m = 0; m < 4; ++m)
        #pragma unroll
        for (int r = 0; r < 4; ++r) {
            float s = part[m][r];
            s += __shfl_down(s, 8);
            s += __shfl_down(s, 4);
            s += __shfl_down(s, 2);
            s += __shfl_down(s, 1);
            part[m][r] = s;
        }
    if (lcol == 0) {
        #pragma unroll
        for (int m = 0; m < 4; ++m)
            #pragma unroll
            for (int r = 0; r < 4; ++r)
                red[w][m * 16 + quad * 4 + r] = part[m][r];
    }
    __syncthreads();

    if (t < 64) {
        int qq = q0 + t;
        if (qq < Q) {
            float s = red[0][t] + red[1][t] + red[2][t] + red[3][t] + P2b[0];
            out[qq] = 1.0f / (1.0f + expf(-s));
        }
    }
}

extern "C" void kernel_launch(void* const* d_in, const int* in_sizes, int n_in,
                              void* d_out, int out_size, void* d_ws, size_t ws_size,
                              hipStream_t stream) {
    const int*   edge_index = (const int*)d_in[0];
    const int*   edges      = (const int*)d_in[1];
    const float* emb        = (const float*)d_in[2];
    const float* W1         = (const float*)d_in[3];
    const float* b1         = (const float*)d_in[4];
    const float* W2         = (const float*)d_in[5];
    const float* b2         = (const float*)d_in[6];
    const float* P1w        = (const float*)d_in[7];
    const float* P1b        = (const float*)d_in[8];
    const float* P2w        = (const float*)d_in[9];
    const float* P2b        = (const float*)d_in[10];

    int E  = in_sizes[0] / 2;
    int Q  = in_sizes[1] / 2;
    int Nn = in_sizes[2] / D;

    const int* rowp = edge_index;
    const int* colp = edge_index + E;
    const int* uq   = edges;
    const int* vq   = edges + Q;
    float* out = (float*)d_out;

    // ---- workspace layout ----
    char* ws = (char*)d_ws;
    size_t off = 0;
    auto alloc = [&](size_t bytes) -> char* {
        char* p = ws + off;
        off = (off + bytes + 255) & ~(size_t)255;
        return p;
    };
    float*          dinv   = (float*)alloc((size_t)Nn * 4);
    int*            rowptr = (int*)  alloc(((size_t)Nn + 1) * 4);
    int*            ebuf   = (int*)  alloc((size_t)E * 4);
    unsigned short* BpW1   = (unsigned short*)alloc(65536 * 2);
    unsigned short* BpW2   = (unsigned short*)alloc(65536 * 2);
    unsigned short* BpP1   = (unsigned short*)alloc(65536 * 2);
    unsigned short* hbuf   = (unsigned short*)alloc((size_t)Nn * D * 2);  // bf16
    unsigned short* xbuf   = (unsigned short*)alloc((size_t)Nn * D * 2);  // bf16

    // CSR temporaries aliased into xbuf (dead until first k_agg writes it)
    int* degi  = (int*)xbuf;
    int* fill  = degi + Nn;
    int* bsums = degi + 2 * Nn;

    int nb;
    int nscan = (Nn + SCAN_CHUNK - 1) / SCAN_CHUNK;

    // CSR build (5 kernels; bsums scan folded into k_scan_add_dinv)
    nb = (2 * Nn + 255) / 256; k_zero_int<<<nb, 256, 0, stream>>>(degi, 2 * Nn);
    nb = (E + 255) / 256;      k_count_int<<<nb, 256, 0, stream>>>(rowp, degi, E);
    k_scan_block<<<nscan, 256, 0, stream>>>(degi, rowptr, bsums, Nn);
    nb = (Nn + 255) / 256;     k_scan_add_dinv<<<nb, 256, 0, stream>>>(rowptr, bsums, degi, dinv, Nn, E, nscan);
    nb = (E + 255) / 256;      k_bucket<<<nb, 256, 0, stream>>>(rowp, colp, rowptr, fill, ebuf, E);

    // pack all three weights for MFMA B operand (one launch)
    k_packB3<<<768, 256, 0, stream>>>(W1, W2, P1w, BpW1, BpW2, BpP1);

    // conv1: h = emb @ W1 (MFMA, fp32 A) ; x1 = relu(norm-agg(h) + b1)  [bf16]
    nb = (Nn + 31) / 32; k_gemm_mfma<<<nb, 256, 0, stream>>>((const void*)emb, 1, BpW1, hbuf, Nn);
    nb = (Nn + 7) / 8;   k_agg<<<nb, 256, 0, stream>>>(hbuf, rowptr, ebuf, dinv, b1, xbuf, Nn, 1);

    // conv2: h = x1 @ W2 (MFMA, bf16 A) ; x2 = norm-agg(h) + b2          [bf16]
    nb = (Nn + 31) / 32; k_gemm_mfma<<<nb, 256, 0, stream>>>((const void*)xbuf, 0, BpW2, hbuf, Nn);
    nb = (Nn + 7) / 8;   k_agg<<<nb, 256, 0, stream>>>(hbuf, rowptr, ebuf, dinv, b2, xbuf, Nn, 0);

    // link predictor v2 (verified 60.5 us): 64 queries/block, block-shared product tile
    nb = (Q + 63) / 64;  k_linkpred<<<nb, 256, 0, stream>>>(uq, vq, xbuf, BpP1, P1b, P2w, P2b, out, Q);
}

// Round 7
// 388.326 us; speedup vs baseline: 1.3481x; 1.0373x over previous
//
#include <hip/hip_runtime.h>
#include <math.h>

#define D 256
#define SCAN_CHUNK 1024
#define GPITCH 264    // bf16 LDS pitch for MFMA A tiles (pad 8) — verified pattern r3-r9
#define PPITCH 264    // product tile pitch for linkpred (same verified MFMA-A pattern)

typedef __attribute__((ext_vector_type(8))) short frag_ab;   // 8 bf16
typedef __attribute__((ext_vector_type(4))) float frag_cd;   // 4 fp32

__device__ inline unsigned short f2b(float f) {
    unsigned int u = __float_as_uint(f);
    u += 0x7fffu + ((u >> 16) & 1u);
    return (unsigned short)(u >> 16);
}
__device__ inline float b2f(unsigned short h) {
    return __uint_as_float(((unsigned int)h) << 16);
}
// elementwise product of two packed bf16 pairs -> packed bf16 pair (TRUNCATING, 7 VALU ops)
__device__ inline unsigned int bmul2t(unsigned int a, unsigned int b) {
    float a0 = __uint_as_float(a << 16);
    float a1 = __uint_as_float(a & 0xffff0000u);
    float b0 = __uint_as_float(b << 16);
    float b1 = __uint_as_float(b & 0xffff0000u);
    float p0 = a0 * b0, p1 = a1 * b1;
    // out = (hi16(p1) << 16) | hi16(p0)
    return __builtin_amdgcn_perm(__float_as_uint(p1), __float_as_uint(p0), 0x07060302);
}

// ---------- prefix scan (2 stages); excl written into rowptr ----------
__global__ __launch_bounds__(256) void k_scan_block(const int* __restrict__ deg, int* __restrict__ excl,
                                                    int* __restrict__ bsums, int n) {
    __shared__ int s[256];
    int blk = blockIdx.x, t = threadIdx.x;
    int base = blk * SCAN_CHUNK + t * 4;
    int v0 = (base + 0 < n) ? deg[base + 0] : 0;
    int v1 = (base + 1 < n) ? deg[base + 1] : 0;
    int v2 = (base + 2 < n) ? deg[base + 2] : 0;
    int v3 = (base + 3 < n) ? deg[base + 3] : 0;
    int tsum = v0 + v1 + v2 + v3;
    s[t] = tsum;
    __syncthreads();
    for (int off = 1; off < 256; off <<= 1) {
        int x = (t >= off) ? s[t - off] : 0;
        __syncthreads();
        s[t] += x;
        __syncthreads();
    }
    int run = s[t] - tsum;
    if (t == 255) bsums[blk] = s[255];
    if (base + 0 < n) excl[base + 0] = run;
    run += v0;
    if (base + 1 < n) excl[base + 1] = run;
    run += v1;
    if (base + 2 < n) excl[base + 2] = run;
    run += v2;
    if (base + 3 < n) excl[base + 3] = run;
}

// fused: every block locally exclusive-scans bsums (nb<=256), then
// rowptr[i] += scanned[i/SCAN_CHUNK] AND dinv[i] = rsqrt(deg[i]+1).
__global__ __launch_bounds__(256) void k_scan_add_dinv(int* __restrict__ rowptr, const int* __restrict__ bsums,
                                                       const int* __restrict__ deg, float* __restrict__ dinv,
                                                       int n, int total, int nb) {
    __shared__ int s[256];
    int t = threadIdx.x;
    int v = (t < nb) ? bsums[t] : 0;
    s[t] = v;
    __syncthreads();
    for (int off = 1; off < 256; off <<= 1) {
        int x = (t >= off) ? s[t - off] : 0;
        __syncthreads();
        s[t] += x;
        __syncthreads();
    }
    int excl = s[t] - v;
    __syncthreads();
    s[t] = excl;
    __syncthreads();
    int i = blockIdx.x * 256 + t;
    if (i < n) {
        rowptr[i] += s[i >> 10];   // SCAN_CHUNK = 1024
        dinv[i] = rsqrtf((float)(deg[i] + 1));
    }
    if (i == 0) rowptr[n] = total;
}

// ---------- bucket edges into CSR (r1-verified form: plain col index) ----------
__global__ void k_bucket(const int* __restrict__ row, const int* __restrict__ col,
                         const int* __restrict__ rowptr, int* __restrict__ fill,
                         int* __restrict__ ebuf, int E) {
    int e = blockIdx.x * 256 + threadIdx.x;
    if (e >= E) return;
    int r = row[e];
    int pos = atomicAdd(&fill[r], 1);
    ebuf[rowptr[r] + pos] = col[e];
}

// ---------- merged: pack 3 weights (blocks 0..767) + degree count (blocks 768..) ----------
// Independent work fused into one dispatch to cut a launch gap (r7).
__global__ void k_pack_count(const float* __restrict__ Wa, const float* __restrict__ Wb,
                             const float* __restrict__ Wc,
                             unsigned short* __restrict__ Ba, unsigned short* __restrict__ Bb,
                             unsigned short* __restrict__ Bc,
                             const int* __restrict__ row, int* __restrict__ deg, int E) {
    int blk = blockIdx.x;
    if (blk < 768) {
        int which = blk >> 8;
        int i = (blk & 255) * 256 + threadIdx.x;   // 65536 per weight
        const float* W = (which == 0) ? Wa : (which == 1) ? Wb : Wc;
        unsigned short* Bp = (which == 0) ? Ba : (which == 1) ? Bb : Bc;
        int ntile = i >> 12;
        int kt = (i >> 9) & 7;
        int lane = (i >> 3) & 63;
        int j = i & 7;
        int k = kt * 32 + (lane >> 4) * 8 + j;
        int n = ntile * 16 + (lane & 15);
        Bp[i] = f2b(W[k * D + n]);
    } else {
        int e = (blk - 768) * 256 + threadIdx.x;
        if (e < E) atomicAdd(&deg[row[e]], 1);
    }
}

// ---------- MFMA GEMM v3 (r7): 32 rows, 2m x 4n per wave (linkpred-verified layout) ----------
// r1 layout had waves 0/2 (1/3) loading the SAME B-half: 256 KB B-traffic/block.
// v3: each wave covers distinct ntiles and both mtiles -> 128 KB/block (1x B, no
// redundancy), same 17 KB LDS / full occupancy. MFMA math and K-order unchanged.
__global__ __launch_bounds__(256) void k_gemm_mfma(const void* __restrict__ X, int xIsF32,
                                                   const unsigned short* __restrict__ Bpack,
                                                   unsigned short* __restrict__ H, int nrows) {
    __shared__ unsigned short As[32 * GPITCH];
    int t = threadIdx.x;
    int rowBase = blockIdx.x * 32;

    {
        int q = t >> 3, c0 = t & 7;    // 8 threads per row, 32 rows
        int r = rowBase + q;
        if (xIsF32) {
            const uint4* xr = (const uint4*)((const float*)X + (size_t)r * D);
            #pragma unroll
            for (int i = 0; i < 4; ++i) {
                int c = c0 + 8 * i;    // 16B bf16 chunk (8 cols), needs 32B of fp32
                uint4 lo4 = make_uint4(0, 0, 0, 0), hi4 = make_uint4(0, 0, 0, 0);
                if (r < nrows) { lo4 = xr[2 * c]; hi4 = xr[2 * c + 1]; }
                uint4 o;
                o.x = (unsigned int)f2b(__uint_as_float(lo4.x)) | ((unsigned int)f2b(__uint_as_float(lo4.y)) << 16);
                o.y = (unsigned int)f2b(__uint_as_float(lo4.z)) | ((unsigned int)f2b(__uint_as_float(lo4.w)) << 16);
                o.z = (unsigned int)f2b(__uint_as_float(hi4.x)) | ((unsigned int)f2b(__uint_as_float(hi4.y)) << 16);
                o.w = (unsigned int)f2b(__uint_as_float(hi4.z)) | ((unsigned int)f2b(__uint_as_float(hi4.w)) << 16);
                *(uint4*)&As[q * GPITCH + c * 8] = o;
            }
        } else {
            const uint4* xr = (const uint4*)((const unsigned short*)X + (size_t)r * D);
            #pragma unroll
            for (int i = 0; i < 4; ++i) {
                int c = c0 + 8 * i;    // 16B chunk = 8 bf16
                uint4 v = make_uint4(0, 0, 0, 0);
                if (r < nrows) v = xr[c];
                *(uint4*)&As[q * GPITCH + c * 8] = v;
            }
        }
    }
    __syncthreads();

    int w = t >> 6, lane = t & 63;
    int quad = lane >> 4, lcol = lane & 15;

    frag_cd acc[2][4];
    #pragma unroll
    for (int m = 0; m < 2; ++m)
        #pragma unroll
        for (int jn = 0; jn < 4; ++jn) acc[m][jn] = (frag_cd){0.f, 0.f, 0.f, 0.f};

    const frag_ab* bp = (const frag_ab*)Bpack;
    for (int kt = 0; kt < 8; ++kt) {
        frag_ab a0 = *(const frag_ab*)&As[(lcol) * GPITCH + kt * 32 + quad * 8];
        frag_ab a1 = *(const frag_ab*)&As[(16 + lcol) * GPITCH + kt * 32 + quad * 8];
        #pragma unroll
        for (int jn = 0; jn < 4; ++jn) {
            frag_ab b = bp[((w * 4 + jn) * 8 + kt) * 64 + lane];
            acc[0][jn] = __builtin_amdgcn_mfma_f32_16x16x32_bf16(a0, b, acc[0][jn], 0, 0, 0);
            acc[1][jn] = __builtin_amdgcn_mfma_f32_16x16x32_bf16(a1, b, acc[1][jn], 0, 0, 0);
        }
    }

    #pragma unroll
    for (int jn = 0; jn < 4; ++jn) {
        int col = (w * 4 + jn) * 16 + lcol;
        #pragma unroll
        for (int m = 0; m < 2; ++m)
            #pragma unroll
            for (int r = 0; r < 4; ++r) {
                int row = rowBase + m * 16 + quad * 4 + r;
                if (row < nrows) H[(size_t)row * D + col] = f2b(acc[m][jn][r]);
            }
    }
}

// ---------- aggregate by gather (VERIFIED ~59.0 us, 4x consistent): at random-line
// fabric ceiling (188 MB/dispatch ~= per-XCD compulsory distinct-row re-fetch).
// Post-mortems: 8-deep (r3) neutral; XCD-chunked (r4) 2x regression. DO NOT TOUCH.
__device__ inline void fma8(uint4 p, float nw, float* a) {
    a[0] = fmaf(b2f((unsigned short)(p.x & 0xffffu)), nw, a[0]);
    a[1] = fmaf(b2f((unsigned short)(p.x >> 16)),     nw, a[1]);
    a[2] = fmaf(b2f((unsigned short)(p.y & 0xffffu)), nw, a[2]);
    a[3] = fmaf(b2f((unsigned short)(p.y >> 16)),     nw, a[3]);
    a[4] = fmaf(b2f((unsigned short)(p.z & 0xffffu)), nw, a[4]);
    a[5] = fmaf(b2f((unsigned short)(p.z >> 16)),     nw, a[5]);
    a[6] = fmaf(b2f((unsigned short)(p.w & 0xffffu)), nw, a[6]);
    a[7] = fmaf(b2f((unsigned short)(p.w >> 16)),     nw, a[7]);
}

__global__ __launch_bounds__(256) void k_agg(const unsigned short* __restrict__ Hh,
                                             const int* __restrict__ rowptr, const int* __restrict__ ebuf,
                                             const float* __restrict__ dinv, const float* __restrict__ b,
                                             unsigned short* __restrict__ Xo, int n, int relu) {
    int w = threadIdx.x >> 6, lane = threadIdx.x & 63;
    int half = lane >> 5, sub = lane & 31;
    int node = (blockIdx.x * 4 + w) * 2 + half;
    if (node >= n) return;
    int c8 = sub * 8;

    float dn = dinv[node];
    float self = dn * dn;

    float acc[8];
    {
        uint4 hp = *(const uint4*)&Hh[(size_t)node * D + c8];
        float4 b0 = *(const float4*)&b[c8];
        float4 b1 = *(const float4*)&b[c8 + 4];
        acc[0] = b0.x; acc[1] = b0.y; acc[2] = b0.z; acc[3] = b0.w;
        acc[4] = b1.x; acc[5] = b1.y; acc[6] = b1.z; acc[7] = b1.w;
        fma8(hp, self, acc);
    }

    int beg = rowptr[node], end = rowptr[node + 1];
    int j = beg;
    for (; j + 3 < end; j += 4) {
        int cA = ebuf[j], cB = ebuf[j + 1], cC = ebuf[j + 2], cD = ebuf[j + 3];
        float nA = dn * dinv[cA], nB = dn * dinv[cB], nC = dn * dinv[cC], nD = dn * dinv[cD];
        uint4 pA = *(const uint4*)&Hh[(size_t)cA * D + c8];
        uint4 pB = *(const uint4*)&Hh[(size_t)cB * D + c8];
        uint4 pC = *(const uint4*)&Hh[(size_t)cC * D + c8];
        uint4 pD = *(const uint4*)&Hh[(size_t)cD * D + c8];
        fma8(pA, nA, acc);
        fma8(pB, nB, acc);
        fma8(pC, nC, acc);
        fma8(pD, nD, acc);
    }
    for (; j < end; ++j) {
        int cA = ebuf[j];
        uint4 pA = *(const uint4*)&Hh[(size_t)cA * D + c8];
        fma8(pA, dn * dinv[cA], acc);
    }
    if (relu) {
        #pragma unroll
        for (int i = 0; i < 8; ++i) acc[i] = fmaxf(acc[i], 0.f);
    }
    uint4 pk;
    pk.x = (unsigned int)f2b(acc[0]) | ((unsigned int)f2b(acc[1]) << 16);
    pk.y = (unsigned int)f2b(acc[2]) | ((unsigned int)f2b(acc[3]) << 16);
    pk.z = (unsigned int)f2b(acc[4]) | ((unsigned int)f2b(acc[5]) << 16);
    pk.w = (unsigned int)f2b(acc[6]) | ((unsigned int)f2b(acc[7]) << 16);
    *(uint4*)&Xo[(size_t)node * D + c8] = pk;
}

// ---------- link predictor v2 (VERIFIED 60.5 us): 64 q/block, block-shared product tile ----------
// Products computed ONCE per block; M=64 halves B L2-traffic per query.
// NOTE: async global_load_lds gather variant measured 84.5 us (r2) — do NOT reintroduce.
__global__ __launch_bounds__(256, 4) void k_linkpred(const int* __restrict__ u, const int* __restrict__ v,
                                                     const unsigned short* __restrict__ X16,
                                                     const unsigned short* __restrict__ Bpack,
                                                     const float* __restrict__ P1b,
                                                     const float* __restrict__ P2w, const float* __restrict__ P2b,
                                                     float* __restrict__ out, int Q) {
    __shared__ unsigned short P[64 * PPITCH];   // 33,792 B product tile (MFMA-A layout)
    __shared__ float red[4][64];

    int t = threadIdx.x;
    int q0 = blockIdx.x * 64;

    // ---- stage 0: gather endpoint rows from global, multiply, write product tile ----
    {
        int q = t >> 2, c0 = t & 3;
        int qq = q0 + q;
        int qc = (qq < Q) ? qq : 0;
        const uint4* ur = (const uint4*)(X16 + (size_t)u[qc] * D);
        const uint4* vr = (const uint4*)(X16 + (size_t)v[qc] * D);
        unsigned short* prow = &P[q * PPITCH];
        #pragma unroll
        for (int i = 0; i < 8; ++i) {
            int c = c0 + 4 * i;
            uint4 a = ur[c];
            uint4 b = vr[c];
            uint4 p;
            p.x = bmul2t(a.x, b.x);
            p.y = bmul2t(a.y, b.y);
            p.z = bmul2t(a.z, b.z);
            p.w = bmul2t(a.w, b.w);
            *(uint4*)(prow + c * 8) = p;
        }
    }
    __syncthreads();

    // ---- stage 1: MFMA, 4 m-tiles x 4 n-tiles per wave ----
    int w = t >> 6, lane = t & 63;
    int quad = lane >> 4, lcol = lane & 15;

    frag_cd acc[4][4];
    #pragma unroll
    for (int m = 0; m < 4; ++m)
        #pragma unroll
        for (int jn = 0; jn < 4; ++jn) acc[m][jn] = (frag_cd){0.f, 0.f, 0.f, 0.f};

    const frag_ab* bp = (const frag_ab*)Bpack;
    for (int kt = 0; kt < 8; ++kt) {
        frag_ab a[4];
        #pragma unroll
        for (int m = 0; m < 4; ++m)
            a[m] = *(const frag_ab*)&P[(m * 16 + lcol) * PPITCH + kt * 32 + quad * 8];
        #pragma unroll
        for (int jn = 0; jn < 4; ++jn) {
            frag_ab b = bp[((w * 4 + jn) * 8 + kt) * 64 + lane];
            #pragma unroll
            for (int m = 0; m < 4; ++m)
                acc[m][jn] = __builtin_amdgcn_mfma_f32_16x16x32_bf16(a[m], b, acc[m][jn], 0, 0, 0);
        }
    }

    // ---- epilogue: relu(H+b1) . P2w, partial over this wave's 4 ntiles ----
    float part[4][4] = {{0.f,0.f,0.f,0.f},{0.f,0.f,0.f,0.f},{0.f,0.f,0.f,0.f},{0.f,0.f,0.f,0.f}};
    #pragma unroll
    for (int jn = 0; jn < 4; ++jn) {
        int col = (w * 4 + jn) * 16 + lcol;
        float bb = P1b[col];
        float pw = P2w[col];
        #pragma unroll
        for (int m = 0; m < 4; ++m)
            #pragma unroll
            for (int r = 0; r < 4; ++r)
                part[m][r] = fmaf(fmaxf(acc[m][jn][r] + bb, 0.f), pw, part[m][r]);
    }
    #pragma unroll
    for (int m = 0; m < 4; ++m)
        #pragma unroll
        for (int r = 0; r < 4; ++r) {
            float s = part[m][r];
            s += __shfl_down(s, 8);
            s += __shfl_down(s, 4);
            s += __shfl_down(s, 2);
            s += __shfl_down(s, 1);
            part[m][r] = s;
        }
    if (lcol == 0) {
        #pragma unroll
        for (int m = 0; m < 4; ++m)
            #pragma unroll
            for (int r = 0; r < 4; ++r)
                red[w][m * 16 + quad * 4 + r] = part[m][r];
    }
    __syncthreads();

    if (t < 64) {
        int qq = q0 + t;
        if (qq < Q) {
            float s = red[0][t] + red[1][t] + red[2][t] + red[3][t] + P2b[0];
            out[qq] = 1.0f / (1.0f + expf(-s));
        }
    }
}

extern "C" void kernel_launch(void* const* d_in, const int* in_sizes, int n_in,
                              void* d_out, int out_size, void* d_ws, size_t ws_size,
                              hipStream_t stream) {
    const int*   edge_index = (const int*)d_in[0];
    const int*   edges      = (const int*)d_in[1];
    const float* emb        = (const float*)d_in[2];
    const float* W1         = (const float*)d_in[3];
    const float* b1         = (const float*)d_in[4];
    const float* W2         = (const float*)d_in[5];
    const float* b2         = (const float*)d_in[6];
    const float* P1w        = (const float*)d_in[7];
    const float* P1b        = (const float*)d_in[8];
    const float* P2w        = (const float*)d_in[9];
    const float* P2b        = (const float*)d_in[10];

    int E  = in_sizes[0] / 2;
    int Q  = in_sizes[1] / 2;
    int Nn = in_sizes[2] / D;

    const int* rowp = edge_index;
    const int* colp = edge_index + E;
    const int* uq   = edges;
    const int* vq   = edges + Q;
    float* out = (float*)d_out;

    // ---- workspace layout ----
    char* ws = (char*)d_ws;
    size_t off = 0;
    auto alloc = [&](size_t bytes) -> char* {
        char* p = ws + off;
        off = (off + bytes + 255) & ~(size_t)255;
        return p;
    };
    float*          dinv   = (float*)alloc((size_t)Nn * 4);
    int*            rowptr = (int*)  alloc(((size_t)Nn + 1) * 4);
    int*            ebuf   = (int*)  alloc((size_t)E * 4);
    unsigned short* BpW1   = (unsigned short*)alloc(65536 * 2);
    unsigned short* BpW2   = (unsigned short*)alloc(65536 * 2);
    unsigned short* BpP1   = (unsigned short*)alloc(65536 * 2);
    unsigned short* hbuf   = (unsigned short*)alloc((size_t)Nn * D * 2);  // bf16
    unsigned short* xbuf   = (unsigned short*)alloc((size_t)Nn * D * 2);  // bf16

    // CSR temporaries aliased into xbuf (dead until first k_agg writes it)
    int* degi  = (int*)xbuf;
    int* fill  = degi + Nn;
    int* bsums = degi + 2 * Nn;

    int nb;
    int nscan = (Nn + SCAN_CHUNK - 1) / SCAN_CHUNK;

    // zero deg+fill via DMA memset (replaces k_zero_int launch)
    hipMemsetAsync(degi, 0, (size_t)(2 * Nn) * 4, stream);

    // pack weights + degree count in ONE dispatch (independent work)
    nb = 768 + (E + 255) / 256;
    k_pack_count<<<nb, 256, 0, stream>>>(W1, W2, P1w, BpW1, BpW2, BpP1, rowp, degi, E);

    // CSR build
    k_scan_block<<<nscan, 256, 0, stream>>>(degi, rowptr, bsums, Nn);
    nb = (Nn + 255) / 256;     k_scan_add_dinv<<<nb, 256, 0, stream>>>(rowptr, bsums, degi, dinv, Nn, E, nscan);
    nb = (E + 255) / 256;      k_bucket<<<nb, 256, 0, stream>>>(rowp, colp, rowptr, fill, ebuf, E);

    // conv1: h = emb @ W1 (MFMA, fp32 A) ; x1 = relu(norm-agg(h) + b1)  [bf16]
    nb = (Nn + 31) / 32; k_gemm_mfma<<<nb, 256, 0, stream>>>((const void*)emb, 1, BpW1, hbuf, Nn);
    nb = (Nn + 7) / 8;   k_agg<<<nb, 256, 0, stream>>>(hbuf, rowptr, ebuf, dinv, b1, xbuf, Nn, 1);

    // conv2: h = x1 @ W2 (MFMA, bf16 A) ; x2 = norm-agg(h) + b2          [bf16]
    nb = (Nn + 31) / 32; k_gemm_mfma<<<nb, 256, 0, stream>>>((const void*)xbuf, 0, BpW2, hbuf, Nn);
    nb = (Nn + 7) / 8;   k_agg<<<nb, 256, 0, stream>>>(hbuf, rowptr, ebuf, dinv, b2, xbuf, Nn, 0);

    // link predictor v2 (verified 60.5 us): 64 queries/block, block-shared product tile
    nb = (Q + 63) / 64;  k_linkpred<<<nb, 256, 0, stream>>>(uq, vq, xbuf, BpP1, P1b, P2w, P2b, out, Q);
}